// Round 1
// baseline (80.554 us; speedup 1.0000x reference)
//
#include <hip/hip_runtime.h>
#include <math.h>

// Problem constants (fixed by the reference).
#define BB 128
#define II 256
#define OO 4096
#define DECAY 0.95f

constexpr int TB  = 16;        // bi rows per block (4 per wave)
constexpr int TO  = 64;        // o cols per block (one per lane)
constexpr int IC  = 64;        // i-chunk staged in LDS
constexpr int PAD = 4;         // +4 floats row pad -> uniform b128 bank spread
constexpr int LDW = IC + PAD;  // 68

__global__ __launch_bounds__(256) void stimulus_linf_kernel(
    const float* __restrict__ x,     // (B, I)
    const float* __restrict__ stim,  // (O, I)
    const float* __restrict__ a,     // (O,)
    const float* __restrict__ b,     // (O,)
    const float* __restrict__ state, // (B, O)
    float* __restrict__ out)         // (B, O)
{
    __shared__ float s_stim[TO][LDW];
    __shared__ float s_x[TB][LDW];

    const int tid  = threadIdx.x;
    const int lane = tid & 63;
    const int wave = tid >> 6;

    // 64 o-tiles x 8 bi-tiles. Blocks sharing an o-tile sit 64 apart
    // (same blockIdx % 8) -> same XCD under round-robin dispatch -> the
    // shared stim tile stays resident in that XCD's L2.
    const int o_tile  = blockIdx.x & 63;
    const int bi_tile = blockIdx.x >> 6;
    const int o_base  = o_tile * TO;
    const int bi_base = bi_tile * TB;

    float d[4] = {0.f, 0.f, 0.f, 0.f};  // |.| >= 0 so 0-init is exact

    for (int ic = 0; ic < II; ic += IC) {
        // ---- stage stim tile: TO x IC = 4096 floats = 1024 float4 ----
        #pragma unroll
        for (int k = 0; k < 4; ++k) {
            const int idx = tid + k * 256;
            const int row = idx >> 4;   // 16 float4 per row
            const int c4  = idx & 15;
            const float4 v = *reinterpret_cast<const float4*>(
                &stim[(o_base + row) * II + ic + c4 * 4]);
            *reinterpret_cast<float4*>(&s_stim[row][c4 * 4]) = v;
        }
        // ---- stage x tile: TB x IC = 1024 floats = 256 float4 ----
        {
            const int row = tid >> 4;
            const int c4  = tid & 15;
            const float4 v = *reinterpret_cast<const float4*>(
                &x[(bi_base + row) * II + ic + c4 * 4]);
            *reinterpret_cast<float4*>(&s_x[row][c4 * 4]) = v;
        }
        __syncthreads();

        // ---- compute: each lane = one o; each wave owns 4 bi rows ----
        const int rb = wave * 4;
        #pragma unroll
        for (int i4 = 0; i4 < IC / 4; ++i4) {
            const float4 s4 =
                *reinterpret_cast<const float4*>(&s_stim[lane][i4 * 4]);
            #pragma unroll
            for (int r = 0; r < 4; ++r) {
                // wave-uniform address -> LDS broadcast read (cheap)
                const float4 xv =
                    *reinterpret_cast<const float4*>(&s_x[rb + r][i4 * 4]);
                const float m01 =
                    fmaxf(fabsf(xv.x - s4.x), fabsf(xv.y - s4.y));
                const float m23 =
                    fmaxf(fabsf(xv.z - s4.z), fabsf(xv.w - s4.w));
                // fmax(fmax) chain -> v_max3_f32
                d[r] = fmaxf(d[r], fmaxf(m01, m23));
            }
        }
        __syncthreads();  // protect LDS before next chunk's staging
    }

    // ---- epilogue: sigmoid((a - d) * b); state*DECAY + value ----
    const int o  = o_base + lane;
    const float av = a[o];
    const float bv = b[o];
    #pragma unroll
    for (int r = 0; r < 4; ++r) {
        const int bi = bi_base + wave * 4 + r;
        const float z   = (av - d[r]) * bv;
        const float val = 1.f / (1.f + __expf(-z));
        out[bi * OO + o] = state[bi * OO + o] * DECAY + val;
    }
}

extern "C" void kernel_launch(void* const* d_in, const int* in_sizes, int n_in,
                              void* d_out, int out_size, void* d_ws, size_t ws_size,
                              hipStream_t stream) {
    const float* x     = (const float*)d_in[0];
    const float* stim  = (const float*)d_in[1];
    const float* a     = (const float*)d_in[2];
    const float* b     = (const float*)d_in[3];
    const float* state = (const float*)d_in[4];
    float* out = (float*)d_out;

    const dim3 grid((OO / TO) * (BB / TB));  // 64 * 8 = 512 blocks
    const dim3 block(256);
    stimulus_linf_kernel<<<grid, block, 0, stream>>>(x, stim, a, b, state, out);
}

// Round 2
// 78.268 us; speedup vs baseline: 1.0292x; 1.0292x over previous
//
#include <hip/hip_runtime.h>
#include <math.h>

// Problem constants (fixed by the reference).
#define BB 128
#define II 256
#define OO 4096
#define DECAY 0.95f

constexpr int TB  = 16;        // bi rows per block (4 per wave, wave-uniform)
constexpr int TO  = 64;        // o cols per block (one per lane)
constexpr int IC  = 64;        // i-chunk staged in LDS
constexpr int PAD = 4;         // +4 floats row pad -> b128 reads conflict-free
constexpr int LDW = IC + PAD;  // 68

__global__ __launch_bounds__(256) void stimulus_linf_kernel(
    const float* __restrict__ x,     // (B, I)
    const float* __restrict__ stim,  // (O, I)
    const float* __restrict__ a,     // (O,)
    const float* __restrict__ b,     // (O,)
    const float* __restrict__ state, // (B, O)
    float* __restrict__ out)         // (B, O)
{
    __shared__ float s_stim[TO][LDW];   // only stim lives in LDS now (17.4 KB)

    const int tid  = threadIdx.x;
    const int lane = tid & 63;
    const int wave = tid >> 6;

    // 64 o-tiles x 8 bi-tiles; blocks sharing a stim tile sit 64 apart
    // (same blockIdx % 8 -> same XCD) so the tile stays L2-resident.
    const int o_tile  = blockIdx.x & 63;
    const int bi_tile = blockIdx.x >> 6;
    const int o_base  = o_tile * TO;
    const int bi_base = bi_tile * TB;

    // Wave-uniform x-row base, forced scalar: all x reads below become
    // s_load_* on the SMEM pipe (no LDS, no per-lane VMEM for x).
    const int wrow = __builtin_amdgcn_readfirstlane(bi_base + wave * 4);

    float d[4] = {0.f, 0.f, 0.f, 0.f};  // |.| >= 0 so 0-init is exact

    for (int ic = 0; ic < II; ic += IC) {
        // ---- stage stim tile: TO x IC = 4096 floats = 1024 float4 ----
        #pragma unroll
        for (int k = 0; k < 4; ++k) {
            const int idx = tid + k * 256;
            const int row = idx >> 4;   // 16 float4 per row
            const int c4  = idx & 15;
            const float4 v = *reinterpret_cast<const float4*>(
                &stim[(o_base + row) * II + ic + c4 * 4]);
            *reinterpret_cast<float4*>(&s_stim[row][c4 * 4]) = v;
        }
        __syncthreads();

        // Scalar (uniform) x-row pointers for this chunk.
        const float4* xr0 = reinterpret_cast<const float4*>(x + (wrow + 0) * II + ic);
        const float4* xr1 = reinterpret_cast<const float4*>(x + (wrow + 1) * II + ic);
        const float4* xr2 = reinterpret_cast<const float4*>(x + (wrow + 2) * II + ic);
        const float4* xr3 = reinterpret_cast<const float4*>(x + (wrow + 3) * II + ic);

        // ---- compute: lane = one o; wave owns 4 bi rows (scalar x) ----
        #pragma unroll
        for (int i4 = 0; i4 < IC / 4; ++i4) {
            const float4 s4 =
                *reinterpret_cast<const float4*>(&s_stim[lane][i4 * 4]);
            const float4 xv0 = xr0[i4];
            const float4 xv1 = xr1[i4];
            const float4 xv2 = xr2[i4];
            const float4 xv3 = xr3[i4];
            // max(max(d,|a|),|b|) -> v_max3_f32 with abs input modifiers:
            // 4 sub + 2 max3 per 4 elements per row.
            d[0] = fmaxf(fmaxf(d[0], fabsf(xv0.x - s4.x)), fabsf(xv0.y - s4.y));
            d[0] = fmaxf(fmaxf(d[0], fabsf(xv0.z - s4.z)), fabsf(xv0.w - s4.w));
            d[1] = fmaxf(fmaxf(d[1], fabsf(xv1.x - s4.x)), fabsf(xv1.y - s4.y));
            d[1] = fmaxf(fmaxf(d[1], fabsf(xv1.z - s4.z)), fabsf(xv1.w - s4.w));
            d[2] = fmaxf(fmaxf(d[2], fabsf(xv2.x - s4.x)), fabsf(xv2.y - s4.y));
            d[2] = fmaxf(fmaxf(d[2], fabsf(xv2.z - s4.z)), fabsf(xv2.w - s4.w));
            d[3] = fmaxf(fmaxf(d[3], fabsf(xv3.x - s4.x)), fabsf(xv3.y - s4.y));
            d[3] = fmaxf(fmaxf(d[3], fabsf(xv3.z - s4.z)), fabsf(xv3.w - s4.w));
        }
        __syncthreads();  // protect LDS before next chunk's staging
    }

    // ---- epilogue: sigmoid((a - d) * b); state*DECAY + value ----
    const int o  = o_base + lane;
    const float av = a[o];
    const float bv = b[o];
    #pragma unroll
    for (int r = 0; r < 4; ++r) {
        const int bi = bi_base + wave * 4 + r;
        const float z   = (av - d[r]) * bv;
        const float val = 1.f / (1.f + __expf(-z));
        out[bi * OO + o] = state[bi * OO + o] * DECAY + val;
    }
}

extern "C" void kernel_launch(void* const* d_in, const int* in_sizes, int n_in,
                              void* d_out, int out_size, void* d_ws, size_t ws_size,
                              hipStream_t stream) {
    const float* x     = (const float*)d_in[0];
    const float* stim  = (const float*)d_in[1];
    const float* a     = (const float*)d_in[2];
    const float* b     = (const float*)d_in[3];
    const float* state = (const float*)d_in[4];
    float* out = (float*)d_out;

    const dim3 grid((OO / TO) * (BB / TB));  // 64 * 8 = 512 blocks
    const dim3 block(256);
    stimulus_linf_kernel<<<grid, block, 0, stream>>>(x, stim, a, b, state, out);
}